// Round 10
// baseline (261.464 us; speedup 1.0000x reference)
//
#include <hip/hip_runtime.h>
#include <stdint.h>

typedef short bf16x8 __attribute__((ext_vector_type(8)));
typedef float f32x4 __attribute__((ext_vector_type(4)));
typedef unsigned int uint4v __attribute__((ext_vector_type(4)));
typedef unsigned short ushort4v __attribute__((ext_vector_type(4)));
typedef float float4v __attribute__((ext_vector_type(4)));

#define MROWS 18464      // 32*577
#define SEQ   577
#define CDIM  1024
#define SPAD  640
#define W1ELEMS (2048*1024)
#define W2ELEMS (1024*1024)
#define SQC 0.42466089f   // sqrt(0.125 * log2(e)); applied to q AND k (same buffer)

__device__ __forceinline__ unsigned short f2bf(float f) {
  unsigned int u = __float_as_uint(f);
  u += 0x7fffu + ((u >> 16) & 1u);   // RNE
  return (unsigned short)(u >> 16);
}

__device__ __forceinline__ void load_lds16(const void* g, void* lds) {
  __builtin_amdgcn_global_load_lds(
      (const __attribute__((address_space(1))) unsigned int*)(uint64_t)(uintptr_t)g,
      (__attribute__((address_space(3))) unsigned int*)(unsigned int)(uintptr_t)lds,
      16, 0, 0);
}

// ---------------- LayerNorm: x fp32 -> z bf16 ----------------
__global__ __launch_bounds__(256) void ln_kernel(const float* __restrict__ x,
                                                 const float* __restrict__ g,
                                                 const float* __restrict__ b,
                                                 unsigned short* __restrict__ z) {
  const int row = blockIdx.x;
  const int t = threadIdx.x;
  const float4v v = *(const float4v*)(x + (size_t)row * CDIM + t * 4);
  float s  = v[0] + v[1] + v[2] + v[3];
  float ss = v[0]*v[0] + v[1]*v[1] + v[2]*v[2] + v[3]*v[3];
  #pragma unroll
  for (int off = 1; off < 64; off <<= 1) { s += __shfl_xor(s, off); ss += __shfl_xor(ss, off); }
  __shared__ float rs[4], rss[4];
  const int w = t >> 6, l = t & 63;
  if (l == 0) { rs[w] = s; rss[w] = ss; }
  __syncthreads();
  s = rs[0] + rs[1] + rs[2] + rs[3];
  ss = rss[0] + rss[1] + rss[2] + rss[3];
  const float mu = s * (1.0f / CDIM);
  const float var = ss * (1.0f / CDIM) - mu * mu;
  const float rstd = rsqrtf(var + 1e-5f);
  const float4v gv = *(const float4v*)(g + t * 4);
  const float4v bv = *(const float4v*)(b + t * 4);
  ushort4v o;
  #pragma unroll
  for (int j = 0; j < 4; ++j) o[j] = f2bf((v[j] - mu) * rstd * gv[j] + bv[j]);
  *(ushort4v*)(z + (size_t)row * CDIM + t * 4) = o;
}

// -------- pack+convert weights + zero vt's seq-pad columns --------
__global__ __launch_bounds__(256) void conv_kernel(const float* __restrict__ w_in,
                                                   const float* __restrict__ w_out,
                                                   unsigned short* __restrict__ wqv,
                                                   unsigned short* __restrict__ wo,
                                                   unsigned short* __restrict__ vt) {
  const int idx = blockIdx.x * 256 + threadIdx.x;
  const int e = idx * 4;
  if (e < W1ELEMS) {
    const int row = e >> 10;
    const int srow = row < 1024 ? row : row + 1024;
    const float4v v = *(const float4v*)(w_in + (size_t)srow * 1024 + (e & 1023));
    ushort4v o;
    #pragma unroll
    for (int j = 0; j < 4; ++j) o[j] = f2bf(v[j]);
    *(ushort4v*)(wqv + e) = o;
  } else if (e < W1ELEMS + W2ELEMS) {
    const int e2 = e - W1ELEMS;
    const float4v v = *(const float4v*)(w_out + e2);
    ushort4v o;
    #pragma unroll
    for (int j = 0; j < 4; ++j) o[j] = f2bf(v[j]);
    *(ushort4v*)(wo + e2) = o;
  } else {
    const int pidx = idx - (W1ELEMS + W2ELEMS) / 4;   // 0..262143
    const int ic = pidx >> 3, part = pidx & 7;
    *(uint4v*)(vt + (size_t)ic * SPAD + 576 + part * 8) = (uint4v)0u;
  }
}

// ---------------- 256x256 GEMM, 8 waves (2Mx4N), BK=64, 8-phase counted-vmcnt ----------------
// Schedule (per iteration i = K-tiles 2i slot0 / 2i+1 slot1):
//   stages: ph0:B1'(2i+1,s1) ph1:AL'(2i+1) ph2:AH'(2i+1) ph3:B0(2i+2,s0)
//           ph4:B1(2i+2) ph5:AL(2i+2) ph6:AH(2i+2) ph7:B0'(2i+3,s1)
//   vmcnt: 4 @ end ph0/ph4/ph7, 2 @ end ph3 (loads never drain to 0).
//   A halves split by (row&127)<64 so every phase's reads are wave-uniform.
template<int MODE>
__global__ __launch_bounds__(512, 2) void gemm256(const unsigned short* __restrict__ A,
                                                  const unsigned short* __restrict__ B,
                                                  const float* __restrict__ bias,
                                                  void* __restrict__ outp,
                                                  unsigned short* __restrict__ vtout) {
  __shared__ char smem[131072];  // slot s at s*65536: A [256][64] @0, B @+32768
  const int t = threadIdx.x;
  const int w = t >> 6, l = t & 63;
  int p, c;
  if constexpr (MODE == 0) {
    const int L = (blockIdx.x & 7) * 73 + (blockIdx.x >> 3);   // bijective: 584=8*73
    p = L >> 3; c = L & 7;
  } else {
    const int xcd = blockIdx.x & 7, j = blockIdx.x >> 3;       // 292 = 4*37 + 4*36
    const int L = (xcd < 4 ? xcd * 37 : 148 + (xcd - 4) * 36) + j;
    p = L >> 2; c = L & 3;
  }
  const int m0 = p * 256, n0 = c * 256;
  const int wm = w >> 2, wn = w & 3;
  const int g4 = (l >> 4) * 4;
  const int fr = l & 15;
  const int fb = (l >> 4) * 16;
  const int sw = (l & 7) << 4;

  f32x4 acc[8][4];
  #pragma unroll
  for (int i = 0; i < 8; ++i)
    #pragma unroll
    for (int j = 0; j < 4; ++j) acc[i][j] = (f32x4)0.0f;

  const int srow = l >> 3;
  const int scol = ((((l & 7) * 16) ^ ((srow & 7) << 4)) >> 1);
  const int alr = (w < 4) ? w * 16 : 128 + (w - 4) * 16;   // this wave's AL 16-row strip

  int r0 = m0 + alr + srow;       if (r0 > MROWS - 1) r0 = MROWS - 1;
  int r1 = m0 + alr + 8 + srow;   if (r1 > MROWS - 1) r1 = MROWS - 1;
  int r2 = m0 + alr + 64 + srow;  if (r2 > MROWS - 1) r2 = MROWS - 1;
  int r3 = m0 + alr + 72 + srow;  if (r3 > MROWS - 1) r3 = MROWS - 1;
  const unsigned short* pAL0 = A + (size_t)r0 * 1024 + scol;
  const unsigned short* pAL1 = A + (size_t)r1 * 1024 + scol;
  const unsigned short* pAH0 = A + (size_t)r2 * 1024 + scol;
  const unsigned short* pAH1 = A + (size_t)r3 * 1024 + scol;
  const unsigned short* pB00 = B + (size_t)(n0 + w * 16 + srow) * 1024 + scol;
  const unsigned short* pB01 = pB00 + 8 * 1024;
  const unsigned short* pB10 = pB00 + 128 * 1024;
  const unsigned short* pB11 = pB00 + 136 * 1024;

  char* const dAL0 = smem + alr * 128;
  char* const dAH0 = dAL0 + 64 * 128;
  char* const dAL1 = dAL0 + 65536;
  char* const dAH1 = dAH0 + 65536;
  char* const dB0s0 = smem + 32768 + (w * 16) * 128;
  char* const dB1s0 = dB0s0 + 128 * 128;
  char* const dB0s1 = dB0s0 + 65536;
  char* const dB1s1 = dB1s0 + 65536;

  #define STGH(pp0, pp1, dd, kt) { load_lds16((pp0) + (kt) * 64, (dd)); load_lds16((pp1) + (kt) * 64, (dd) + 1024); }
  #define VMC(n) { asm volatile("s_waitcnt vmcnt(" #n ")" ::: "memory"); __builtin_amdgcn_sched_barrier(0); }
  #define BAR __builtin_amdgcn_s_barrier();
  #define RD_A(dst, so, ho, kk) \
    _Pragma("unroll") for (int i2 = 0; i2 < 4; ++i2) \
      dst[i2] = *(const bf16x8*)(smem + (so) + (wm * 128 + (ho) + i2 * 16 + fr) * 128 + (((kk) * 64 + fb) ^ sw));
  #define RD_B(dst, so, kk) \
    _Pragma("unroll") for (int j2 = 0; j2 < 4; ++j2) \
      dst[j2] = *(const bf16x8*)(smem + (so) + 32768 + (wn * 64 + j2 * 16 + fr) * 128 + (((kk) * 64 + fb) ^ sw));
  #define MMA(I0, AF, BF) \
    __builtin_amdgcn_s_setprio(1); \
    _Pragma("unroll") for (int i2 = 0; i2 < 4; ++i2) \
      _Pragma("unroll") for (int j2 = 0; j2 < 4; ++j2) \
        acc[(I0) + i2][j2] = __builtin_amdgcn_mfma_f32_16x16x32_bf16(AF[i2], BF[j2], acc[(I0) + i2][j2], 0, 0, 0); \
    __builtin_amdgcn_s_setprio(0);

  // prologue: stage tiles 0 (slot0) and 1 (slot1) in steady-state-compatible order
  STGH(pB00, pB01, dB0s0, 0) STGH(pB10, pB11, dB1s0, 0)
  STGH(pAL0, pAL1, dAL0, 0)  STGH(pAH0, pAH1, dAH0, 0)
  STGH(pB00, pB01, dB0s1, 1) STGH(pB10, pB11, dB1s1, 1)
  STGH(pAL0, pAL1, dAL1, 1)  STGH(pAH0, pAH1, dAH1, 1)
  VMC(4)
  BAR

  bf16x8 afL[4], afH[4], bf0[4], bf1[4];
  for (int i = 0; i < 8; ++i) {
    const int kA = 2 * i + 2;   // slot0 refill tile
    const int kB = 2 * i + 1;   // slot1 tile being staged ph0-2 (read ph4-7)
    const int kC = 2 * i + 3;   // slot1 refill tile
    // ph0: slot0 kk0, m-low
    RD_B(bf0, 0, 0) RD_A(afL, 0, 0, 0)
    if (i > 0) STGH(pB10, pB11, dB1s1, kB)
    BAR MMA(0, afL, bf0) VMC(4) BAR
    // ph1: slot0 kk0, m-high
    RD_A(afH, 0, 64, 0)
    if (i > 0) STGH(pAL0, pAL1, dAL1, kB)
    BAR MMA(4, afH, bf0) BAR
    // ph2: slot0 kk1, m-low
    RD_B(bf1, 0, 1) RD_A(afL, 0, 0, 1)
    if (i > 0) STGH(pAH0, pAH1, dAH1, kB)
    BAR MMA(0, afL, bf1) BAR
    // ph3: slot0 kk1, m-high
    RD_A(afH, 0, 64, 1)
    if (i < 7) STGH(pB00, pB01, dB0s0, kA)
    BAR MMA(4, afH, bf1) VMC(2) BAR
    // ph4: slot1 kk0, m-low
    RD_B(bf0, 65536, 0) RD_A(afL, 65536, 0, 0)
    if (i < 7) STGH(pB10, pB11, dB1s0, kA)
    BAR MMA(0, afL, bf0) VMC(4) BAR
    // ph5: slot1 kk0, m-high
    RD_A(afH, 65536, 64, 0)
    if (i < 7) STGH(pAL0, pAL1, dAL0, kA)
    BAR MMA(4, afH, bf0) BAR
    // ph6: slot1 kk1, m-low
    RD_B(bf1, 65536, 1) RD_A(afL, 65536, 0, 1)
    if (i < 7) STGH(pAH0, pAH1, dAH0, kA)
    BAR MMA(0, afL, bf1) BAR
    // ph7: slot1 kk1, m-high
    RD_A(afH, 65536, 64, 1)
    if (i < 7) STGH(pB00, pB01, dB0s1, kC)
    BAR MMA(4, afH, bf1) VMC(4) BAR
  }
  #undef STGH
  #undef VMC
  #undef BAR
  #undef RD_A
  #undef RD_B
  #undef MMA
  __syncthreads();  // drains remaining loads; epilogue reuses smem

  if constexpr (MODE == 0) {
    unsigned short* sm = (unsigned short*)smem;   // [128][264] b16 per pass
    const bool isq = (n0 < 1024);
    const float* bb = isq ? (bias + n0) : (bias + 1024 + n0);
    const float scl = isq ? SQC : 1.0f;
    float bcol[4];
    #pragma unroll
    for (int j = 0; j < 4; ++j) bcol[j] = bb[wn * 64 + j * 16 + fr];
    for (int pass = 0; pass < 2; ++pass) {
      if (wm == pass) {
        #pragma unroll
        for (int i = 0; i < 8; ++i)
          #pragma unroll
          for (int j = 0; j < 4; ++j)
            #pragma unroll
            for (int r = 0; r < 4; ++r)
              sm[(i * 16 + g4 + r) * 264 + wn * 64 + j * 16 + fr] =
                  f2bf((acc[i][j][r] + bcol[j]) * scl);
      }
      __syncthreads();
      if (isq) {
        unsigned short* o = (unsigned short*)outp;
        #pragma unroll
        for (int it = 0; it < 8; ++it) {
          const int cid = it * 512 + t;
          const int row = cid >> 5, ch = cid & 31;
          const int grow = m0 + pass * 128 + row;
          if (grow < MROWS)
            *(uint4v*)(o + (size_t)grow * 1024 + n0 + ch * 8) =
                *(const uint4v*)(sm + row * 264 + ch * 8);
        }
      } else {
        const int rowloc = t & 127, chb = t >> 7;   // chb 0..3, 64 channels each
        const int token = m0 + pass * 128 + rowloc;
        if (token < MROWS) {
          const unsigned int nimg = (unsigned int)token / 577u;
          const int s = token - (int)(nimg * 577u);
          unsigned short* op =
              vtout + ((size_t)nimg * 1024 + (n0 - 1024) + chb * 64) * SPAD + s;
          const unsigned short* sp = sm + rowloc * 264 + chb * 64;
          #pragma unroll 8
          for (int it = 0; it < 64; ++it)
            op[(size_t)it * SPAD] = sp[it];
        }
      }
      __syncthreads();
    }
  } else {  // proj fp32: four 64-row passes, [64][260] f32
    float* smf = (float*)smem;
    float bcol[4];
    #pragma unroll
    for (int j = 0; j < 4; ++j) bcol[j] = bias[n0 + wn * 64 + j * 16 + fr];
    float* o = (float*)outp;
    for (int q4 = 0; q4 < 4; ++q4) {
      if (wm == (q4 >> 1)) {
        const int i0 = (q4 & 1) * 4;
        #pragma unroll
        for (int i2 = 0; i2 < 4; ++i2)
          #pragma unroll
          for (int j = 0; j < 4; ++j)
            #pragma unroll
            for (int r = 0; r < 4; ++r)
              smf[(i2 * 16 + g4 + r) * 260 + wn * 64 + j * 16 + fr] =
                  acc[i0 + i2][j][r] + bcol[j];
      }
      __syncthreads();
      #pragma unroll
      for (int it = 0; it < 8; ++it) {
        const int cid = it * 512 + t;
        const int row = cid >> 6, ch = cid & 63;
        const int grow = m0 + q4 * 64 + row;
        if (grow < MROWS)
          *(float4v*)(o + (size_t)grow * 1024 + n0 + ch * 4) =
              *(const float4v*)(smf + row * 260 + ch * 4);
      }
      __syncthreads();
    }
  }
}

// ---------------- flash attention, k = q ('qq'), no-max softmax ----------------
__global__ __launch_bounds__(256) void attn_kernel(const unsigned short* __restrict__ qbuf,
                                                   const unsigned short* __restrict__ vt,
                                                   unsigned short* __restrict__ out) {
  __shared__ char smem[32768];  // buf b at b*16384: K 8KB, V^T 8KB
  const int t = threadIdx.x, w = t >> 6, l = t & 63;
  const int g = l >> 4, fr = l & 15;
  const int bid = blockIdx.x;
  const int xcd = bid & 7, idx = bid >> 3;
  const int nhl = idx / 5;
  const int qb = idx - nhl * 5;
  const int nh = xcd * 64 + nhl;
  const int n = nh >> 4, h = nh & 15;
  const size_t rowbase = (size_t)n * SEQ;
  const int sw = (l & 7) << 4;

  bf16x8 bq[2][2];
  #pragma unroll
  for (int half = 0; half < 2; ++half) {
    const unsigned short* qp =
        qbuf + (rowbase + qb * 128 + half * 64 + w * 16 + fr) * 1024 + h * 64 + g * 8;
    bq[half][0] = *(const bf16x8*)qp;
    bq[half][1] = *(const bf16x8*)(qp + 32);
  }

  const int srow = l >> 3;
  const int scolE = ((((l & 7) * 16) ^ ((srow & 7) << 4)) >> 1);
  const unsigned short* ksrc = qbuf + (rowbase + w * 16 + srow) * 1024 + h * 64 + scolE;
  const unsigned short* vsrc = vt + ((size_t)nh * 64 + w * 16 + srow) * SPAD + scolE;

  f32x4 acc[2][4];
  #pragma unroll
  for (int half = 0; half < 2; ++half)
    #pragma unroll
    for (int cf = 0; cf < 4; ++cf) acc[half][cf] = (f32x4)0.0f;
  float l_run[2] = {0.0f, 0.0f};

  {
    char* kdst = smem + (w * 16) * 128;
    char* vdst = smem + 8192 + (w * 16) * 128;
    load_lds16(ksrc, kdst);
    load_lds16(ksrc + (size_t)8 * 1024, kdst + 1024);
    load_lds16(vsrc, vdst);
    load_lds16(vsrc + 8 * SPAD, vdst + 1024);
  }
  __syncthreads();

  for (int kb = 0; kb < 10; ++kb) {
    const int b = kb & 1;
    const char* kbuf = smem + b * 16384;
    const char* vbuf = kbuf + 8192;

    if (kb < 9) {
      char* kdst = smem + (b ^ 1) * 16384 + (w * 16) * 128;
      char* vdst = kdst + 8192;
      load_lds16(ksrc + (size_t)((kb + 1) * 64) * 1024, kdst);
      load_lds16(ksrc + (size_t)((kb + 1) * 64 + 8) * 1024, kdst + 1024);
      load_lds16(vsrc + (kb + 1) * 64, vdst);
      load_lds16(vsrc + 8 * SPAD + (kb + 1) * 64, vdst + 1024);
    }

    f32x4 s4[2][4];
    #pragma unroll
    for (int half = 0; half < 2; ++half)
      #pragma unroll
      for (int cf = 0; cf < 4; ++cf) s4[half][cf] = (f32x4)0.0f;
    #pragma unroll
    for (int kk = 0; kk < 2; ++kk)
      #pragma unroll
      for (int cf = 0; cf < 4; ++cf) {
        const bf16x8 af = *(const bf16x8*)(kbuf + (cf * 16 + fr) * 128 + ((kk * 64 + g * 16) ^ sw));
        s4[0][cf] = __builtin_amdgcn_mfma_f32_16x16x32_bf16(af, bq[0][kk], s4[0][cf], 0, 0, 0);
        s4[1][cf] = __builtin_amdgcn_mfma_f32_16x16x32_bf16(af, bq[1][kk], s4[1][cf], 0, 0, 0);
      }

    if (kb == 9) {
      #pragma unroll
      for (int half = 0; half < 2; ++half) {
        #pragma unroll
        for (int cf = 0; cf < 4; ++cf)
          #pragma unroll
          for (int r = 0; r < 4; ++r)
            if (cf != 0 || r != 0) s4[half][cf][r] = -__builtin_inff();
        s4[half][0][0] = (g == 0) ? s4[half][0][0] : -__builtin_inff();
      }
    }

    bf16x8 ap[2][2];
    #pragma unroll
    for (int half = 0; half < 2; ++half) {
      float sum = 0.0f;
      #pragma unroll
      for (int cf = 0; cf < 4; ++cf)
        #pragma unroll
        for (int r = 0; r < 4; ++r) {
          const float p2 = __builtin_amdgcn_exp2f(s4[half][cf][r]);
          s4[half][cf][r] = p2;
          sum += p2;
        }
      sum += __shfl_xor(sum, 16);
      sum += __shfl_xor(sum, 32);
      l_run[half] += sum;

      unsigned int pka[4], pkb[4];
      #pragma unroll
      for (int cf = 0; cf < 4; ++cf) {
        asm("v_cvt_pk_bf16_f32 %0, %1, %2" : "=v"(pka[cf]) : "v"(s4[half][cf][0]), "v"(s4[half][cf][1]));
        asm("v_cvt_pk_bf16_f32 %0, %1, %2" : "=v"(pkb[cf]) : "v"(s4[half][cf][2]), "v"(s4[half][cf][3]));
      }
      #pragma unroll
      for (int kk = 0; kk < 2; ++kk) {
        unsigned int a0 = pka[2 * kk], b0 = pka[2 * kk + 1];
        unsigned int a1 = pkb[2 * kk], b1 = pkb[2 * kk + 1];
        asm("v_permlane32_swap_b32 %0, %1" : "+v"(a0), "+v"(b0));
        asm("v_permlane16_swap_b32 %0, %1" : "+v"(a0), "+v"(b0));
        asm("v_permlane32_swap_b32 %0, %1" : "+v"(a1), "+v"(b1));
        asm("v_permlane16_swap_b32 %0, %1" : "+v"(a1), "+v"(b1));
        union { unsigned int i[4]; bf16x8 v; } u;
        u.i[0] = a0; u.i[1] = a1; u.i[2] = b0; u.i[3] = b1;
        ap[half][kk] = u.v;
      }
    }

    #pragma unroll
    for (int kk = 0; kk < 2; ++kk)
      #pragma unroll
      for (int cf = 0; cf < 4; ++cf) {
        const bf16x8 bv = *(const bf16x8*)(vbuf + (cf * 16 + fr) * 128 + ((kk * 64 + g * 16) ^ sw));
        acc[0][cf] = __builtin_amdgcn_mfma_f32_16x16x32_bf16(ap[0][kk], bv, acc[0][cf], 0, 0, 0);
        acc[1][cf] = __builtin_amdgcn_mfma_f32_16x16x32_bf16(ap[1][kk], bv, acc[1][cf], 0, 0, 0);
      }

    __syncthreads();
  }

  #pragma unroll
  for (int half = 0; half < 2; ++half) {
    const float rcp = 1.0f / l_run[half];
    #pragma unroll
    for (int r = 0; r < 4; ++r) {
      const float rr = __shfl(rcp, g * 4 + r);
      const int qg = qb * 128 + half * 64 + w * 16 + g * 4 + r;
      if (qg < SEQ) {
        #pragma unroll
        for (int cf = 0; cf < 4; ++cf)
          out[(rowbase + qg) * 1024 + h * 64 + cf * 16 + fr] = f2bf(acc[half][cf][r] * rr);
      }
    }
  }
}

extern "C" void kernel_launch(void* const* d_in, const int* in_sizes, int n_in,
                              void* d_out, int out_size, void* d_ws, size_t ws_size,
                              hipStream_t stream) {
  const float* x     = (const float*)d_in[0];
  const float* ln_g  = (const float*)d_in[1];
  const float* ln_b  = (const float*)d_in[2];
  const float* w_in  = (const float*)d_in[3];
  const float* b_in  = (const float*)d_in[4];
  const float* w_out = (const float*)d_in[5];
  const float* b_out = (const float*)d_in[6];

  unsigned short* z    = (unsigned short*)d_ws;            // [MROWS][1024] bf16; reused as attn_out
  unsigned short* qbuf = z + (size_t)MROWS * 1024;         // [MROWS][1024] bf16 (q = k, pre-scaled)
  unsigned short* vt   = qbuf + (size_t)MROWS * 1024;      // [32*1024][640] bf16 (V^T)
  unsigned short* wqv  = vt + (size_t)512 * 64 * SPAD;     // [2048][1024] bf16
  unsigned short* wo   = wqv + (size_t)2048 * 1024;        // [1024][1024] bf16

  ln_kernel<<<MROWS, 256, 0, stream>>>(x, ln_g, ln_b, z);
  conv_kernel<<<4096, 256, 0, stream>>>(w_in, w_out, wqv, wo, vt);
  gemm256<0><<<584, 512, 0, stream>>>(z, wqv, b_in, qbuf, vt);
  attn_kernel<<<2560, 256, 0, stream>>>(qbuf, vt, z);
  gemm256<1><<<292, 512, 0, stream>>>(z, wo, b_out, d_out, nullptr);
}

// Round 11
// 247.967 us; speedup vs baseline: 1.0544x; 1.0544x over previous
//
#include <hip/hip_runtime.h>
#include <stdint.h>

typedef short bf16x8 __attribute__((ext_vector_type(8)));
typedef float f32x4 __attribute__((ext_vector_type(4)));
typedef unsigned int uint4v __attribute__((ext_vector_type(4)));
typedef unsigned short ushort4v __attribute__((ext_vector_type(4)));
typedef float float4v __attribute__((ext_vector_type(4)));

#define MROWS 18464      // 32*577
#define SEQ   577
#define CDIM  1024
#define SPAD  640
#define W1ELEMS (2048*1024)
#define W2ELEMS (1024*1024)
#define SQC 0.42466089f   // sqrt(0.125 * log2(e)); applied to q AND k (same buffer)

__device__ __forceinline__ unsigned short f2bf(float f) {
  unsigned int u = __float_as_uint(f);
  u += 0x7fffu + ((u >> 16) & 1u);   // RNE
  return (unsigned short)(u >> 16);
}

__device__ __forceinline__ void load_lds16(const void* g, void* lds) {
  __builtin_amdgcn_global_load_lds(
      (const __attribute__((address_space(1))) unsigned int*)(uint64_t)(uintptr_t)g,
      (__attribute__((address_space(3))) unsigned int*)(unsigned int)(uintptr_t)lds,
      16, 0, 0);
}

// ---------------- LayerNorm: x fp32 -> z bf16 ----------------
__global__ __launch_bounds__(256) void ln_kernel(const float* __restrict__ x,
                                                 const float* __restrict__ g,
                                                 const float* __restrict__ b,
                                                 unsigned short* __restrict__ z) {
  const int row = blockIdx.x;
  const int t = threadIdx.x;
  const float4v v = *(const float4v*)(x + (size_t)row * CDIM + t * 4);
  float s  = v[0] + v[1] + v[2] + v[3];
  float ss = v[0]*v[0] + v[1]*v[1] + v[2]*v[2] + v[3]*v[3];
  #pragma unroll
  for (int off = 1; off < 64; off <<= 1) { s += __shfl_xor(s, off); ss += __shfl_xor(ss, off); }
  __shared__ float rs[4], rss[4];
  const int w = t >> 6, l = t & 63;
  if (l == 0) { rs[w] = s; rss[w] = ss; }
  __syncthreads();
  s = rs[0] + rs[1] + rs[2] + rs[3];
  ss = rss[0] + rss[1] + rss[2] + rss[3];
  const float mu = s * (1.0f / CDIM);
  const float var = ss * (1.0f / CDIM) - mu * mu;
  const float rstd = rsqrtf(var + 1e-5f);
  const float4v gv = *(const float4v*)(g + t * 4);
  const float4v bv = *(const float4v*)(b + t * 4);
  ushort4v o;
  #pragma unroll
  for (int j = 0; j < 4; ++j) o[j] = f2bf((v[j] - mu) * rstd * gv[j] + bv[j]);
  *(ushort4v*)(z + (size_t)row * CDIM + t * 4) = o;
}

// -------- pack+convert weights + zero vt's seq-pad columns --------
__global__ __launch_bounds__(256) void conv_kernel(const float* __restrict__ w_in,
                                                   const float* __restrict__ w_out,
                                                   unsigned short* __restrict__ wqv,
                                                   unsigned short* __restrict__ wo,
                                                   unsigned short* __restrict__ vt) {
  const int idx = blockIdx.x * 256 + threadIdx.x;
  const int e = idx * 4;
  if (e < W1ELEMS) {
    const int row = e >> 10;
    const int srow = row < 1024 ? row : row + 1024;
    const float4v v = *(const float4v*)(w_in + (size_t)srow * 1024 + (e & 1023));
    ushort4v o;
    #pragma unroll
    for (int j = 0; j < 4; ++j) o[j] = f2bf(v[j]);
    *(ushort4v*)(wqv + e) = o;
  } else if (e < W1ELEMS + W2ELEMS) {
    const int e2 = e - W1ELEMS;
    const float4v v = *(const float4v*)(w_out + e2);
    ushort4v o;
    #pragma unroll
    for (int j = 0; j < 4; ++j) o[j] = f2bf(v[j]);
    *(ushort4v*)(wo + e2) = o;
  } else {
    const int pidx = idx - (W1ELEMS + W2ELEMS) / 4;   // 0..262143
    const int ic = pidx >> 3, part = pidx & 7;
    *(uint4v*)(vt + (size_t)ic * SPAD + 576 + part * 8) = (uint4v)0u;
  }
}

// ---------------- 256x256 GEMM, 16 waves (4Mx4N of 64x64), BK=64, dbuf 2-phase ----------------
// 1024 threads, __launch_bounds__(1024,4) caps VGPR at 128 -> 4 waves/SIMD resident.
// acc per wave = 4x4 fragments = 64 VGPR. Staging: 4 gload_lds/thread per K-tile,
// pre-swizzled source, linear LDS dest. Panel-major XCD-chunked grid (R7-proven).
// MODE 0 (qv): 584 blocks; n0<1024 -> q bf16 xSQC; n0>=1024 -> v^T scatter to vt.
// MODE 1 (proj): 292 blocks; fp32 out + bias.
template<int MODE>
__global__ __launch_bounds__(1024, 4) void gemm256(const unsigned short* __restrict__ A,
                                                   const unsigned short* __restrict__ B,
                                                   const float* __restrict__ bias,
                                                   void* __restrict__ outp,
                                                   unsigned short* __restrict__ vtout) {
  __shared__ char smem[131072];  // buf b at b*65536: A [256][64] @0 (32KB), B @32768
  const int t = threadIdx.x;
  const int w = t >> 6, l = t & 63;
  int p, c;
  if constexpr (MODE == 0) {
    const int L = (blockIdx.x & 7) * 73 + (blockIdx.x >> 3);   // bijective: 584=8*73
    p = L >> 3; c = L & 7;
  } else {
    const int xcd = blockIdx.x & 7, j = blockIdx.x >> 3;       // 292 = 4*37 + 4*36
    const int L = (xcd < 4 ? xcd * 37 : 148 + (xcd - 4) * 36) + j;
    p = L >> 2; c = L & 3;
  }
  const int m0 = p * 256, n0 = c * 256;
  const int wm = w >> 2, wn = w & 3;
  const int g4 = (l >> 4) * 4;
  const int fr = l & 15;
  const int fb = (l >> 4) * 16;
  const int sw = (l & 7) << 4;

  f32x4 acc[4][4];
  #pragma unroll
  for (int i = 0; i < 4; ++i)
    #pragma unroll
    for (int j = 0; j < 4; ++j) acc[i][j] = (f32x4)0.0f;

  // staging: wave w covers rows w*16..w*16+15 of A and of B (2 loads each)
  const int srow = l >> 3;
  const int scol = ((((l & 7) * 16) ^ ((srow & 7) << 4)) >> 1);
  int ra0 = m0 + w * 16 + srow;     if (ra0 > MROWS - 1) ra0 = MROWS - 1;
  int ra1 = m0 + w * 16 + 8 + srow; if (ra1 > MROWS - 1) ra1 = MROWS - 1;
  const unsigned short* pA0 = A + (size_t)ra0 * 1024 + scol;
  const unsigned short* pA1 = A + (size_t)ra1 * 1024 + scol;
  const unsigned short* pB0 = B + (size_t)(n0 + w * 16 + srow) * 1024 + scol;
  const unsigned short* pB1 = pB0 + (size_t)8 * 1024;

  #define STG(kt, buf)                                                     \
    {                                                                      \
      char* const dA_ = smem + (buf) * 65536 + w * 2048;                   \
      char* const dB_ = dA_ + 32768;                                       \
      const int k0_ = (kt) * 64;                                           \
      load_lds16(pA0 + k0_, dA_);                                          \
      load_lds16(pA1 + k0_, dA_ + 1024);                                   \
      load_lds16(pB0 + k0_, dB_);                                          \
      load_lds16(pB1 + k0_, dB_ + 1024);                                   \
    }

  STG(0, 0)
  __syncthreads();

  for (int kb = 0; kb < 16; ++kb) {
    const int b = kb & 1;
    if (kb < 15) STG(kb + 1, b ^ 1)
    const char* Ab = smem + b * 65536;
    const char* Bb = Ab + 32768;
    #pragma unroll
    for (int kk = 0; kk < 2; ++kk) {
      bf16x8 af[4], bfr[4];
      #pragma unroll
      for (int i = 0; i < 4; ++i)
        af[i] = *(const bf16x8*)(Ab + (wm * 64 + i * 16 + fr) * 128 + ((kk * 64 + fb) ^ sw));
      #pragma unroll
      for (int j = 0; j < 4; ++j)
        bfr[j] = *(const bf16x8*)(Bb + (wn * 64 + j * 16 + fr) * 128 + ((kk * 64 + fb) ^ sw));
      #pragma unroll
      for (int i = 0; i < 4; ++i)
        #pragma unroll
        for (int j = 0; j < 4; ++j)
          acc[i][j] = __builtin_amdgcn_mfma_f32_16x16x32_bf16(af[i], bfr[j], acc[i][j], 0, 0, 0);
    }
    __syncthreads();
  }
  #undef STG

  if constexpr (MODE == 0) {
    unsigned short* sm = (unsigned short*)smem;   // [64][264] b16 per pass
    const bool isq = (n0 < 1024);
    const float* bb = isq ? (bias + n0) : (bias + 1024 + n0);
    const float scl = isq ? SQC : 1.0f;
    float bcol[4];
    #pragma unroll
    for (int j = 0; j < 4; ++j) bcol[j] = bb[wn * 64 + j * 16 + fr];
    for (int pass = 0; pass < 4; ++pass) {
      if (wm == pass) {
        #pragma unroll
        for (int i = 0; i < 4; ++i)
          #pragma unroll
          for (int j = 0; j < 4; ++j)
            #pragma unroll
            for (int r = 0; r < 4; ++r)
              sm[(i * 16 + g4 + r) * 264 + wn * 64 + j * 16 + fr] =
                  f2bf((acc[i][j][r] + bcol[j]) * scl);
      }
      __syncthreads();
      if (isq) {
        unsigned short* o = (unsigned short*)outp;
        #pragma unroll
        for (int it = 0; it < 2; ++it) {
          const int cid = it * 1024 + t;
          const int row = cid >> 5, ch = cid & 31;
          const int grow = m0 + pass * 64 + row;
          if (grow < MROWS)
            *(uint4v*)(o + (size_t)grow * 1024 + n0 + ch * 8) =
                *(const uint4v*)(sm + row * 264 + ch * 8);
        }
      } else {
        const int tokloc = t & 63, chgrp = t >> 6;   // 16 groups of 16 channels
        const int token = m0 + pass * 64 + tokloc;
        if (token < MROWS) {
          const unsigned int nimg = (unsigned int)token / 577u;
          const int s = token - (int)(nimg * 577u);
          unsigned short* op =
              vtout + ((size_t)nimg * 1024 + (n0 - 1024) + chgrp * 16) * SPAD + s;
          const unsigned short* sp = sm + tokloc * 264 + chgrp * 16;
          #pragma unroll 8
          for (int it = 0; it < 16; ++it)
            op[(size_t)it * SPAD] = sp[it];
        }
      }
      __syncthreads();
    }
  } else {  // proj fp32: four 64-row passes, [64][260] f32
    float* smf = (float*)smem;
    float bcol[4];
    #pragma unroll
    for (int j = 0; j < 4; ++j) bcol[j] = bias[n0 + wn * 64 + j * 16 + fr];
    float* o = (float*)outp;
    for (int pass = 0; pass < 4; ++pass) {
      if (wm == pass) {
        #pragma unroll
        for (int i = 0; i < 4; ++i)
          #pragma unroll
          for (int j = 0; j < 4; ++j)
            #pragma unroll
            for (int r = 0; r < 4; ++r)
              smf[(i * 16 + g4 + r) * 260 + wn * 64 + j * 16 + fr] =
                  acc[i][j][r] + bcol[j];
      }
      __syncthreads();
      #pragma unroll
      for (int it = 0; it < 4; ++it) {
        const int cid = it * 1024 + t;
        const int row = cid >> 6, ch = cid & 63;
        const int grow = m0 + pass * 64 + row;
        if (grow < MROWS)
          *(float4v*)(o + (size_t)grow * 1024 + n0 + ch * 4) =
              *(const float4v*)(smf + row * 260 + ch * 4);
      }
      __syncthreads();
    }
  }
}

// ---------------- flash attention, k = q ('qq'), no-max softmax ----------------
__global__ __launch_bounds__(256) void attn_kernel(const unsigned short* __restrict__ qbuf,
                                                   const unsigned short* __restrict__ vt,
                                                   unsigned short* __restrict__ out) {
  __shared__ char smem[32768];  // buf b at b*16384: K 8KB, V^T 8KB
  const int t = threadIdx.x, w = t >> 6, l = t & 63;
  const int g = l >> 4, fr = l & 15;
  const int bid = blockIdx.x;
  const int xcd = bid & 7, idx = bid >> 3;
  const int nhl = idx / 5;
  const int qb = idx - nhl * 5;
  const int nh = xcd * 64 + nhl;
  const int n = nh >> 4, h = nh & 15;
  const size_t rowbase = (size_t)n * SEQ;
  const int sw = (l & 7) << 4;

  bf16x8 bq[2][2];
  #pragma unroll
  for (int half = 0; half < 2; ++half) {
    const unsigned short* qp =
        qbuf + (rowbase + qb * 128 + half * 64 + w * 16 + fr) * 1024 + h * 64 + g * 8;
    bq[half][0] = *(const bf16x8*)qp;
    bq[half][1] = *(const bf16x8*)(qp + 32);
  }

  const int srow = l >> 3;
  const int scolE = ((((l & 7) * 16) ^ ((srow & 7) << 4)) >> 1);
  const unsigned short* ksrc = qbuf + (rowbase + w * 16 + srow) * 1024 + h * 64 + scolE;
  const unsigned short* vsrc = vt + ((size_t)nh * 64 + w * 16 + srow) * SPAD + scolE;

  f32x4 acc[2][4];
  #pragma unroll
  for (int half = 0; half < 2; ++half)
    #pragma unroll
    for (int cf = 0; cf < 4; ++cf) acc[half][cf] = (f32x4)0.0f;
  float l_run[2] = {0.0f, 0.0f};

  {
    char* kdst = smem + (w * 16) * 128;
    char* vdst = smem + 8192 + (w * 16) * 128;
    load_lds16(ksrc, kdst);
    load_lds16(ksrc + (size_t)8 * 1024, kdst + 1024);
    load_lds16(vsrc, vdst);
    load_lds16(vsrc + 8 * SPAD, vdst + 1024);
  }
  __syncthreads();

  for (int kb = 0; kb < 10; ++kb) {
    const int b = kb & 1;
    const char* kbuf = smem + b * 16384;
    const char* vbuf = kbuf + 8192;

    if (kb < 9) {
      char* kdst = smem + (b ^ 1) * 16384 + (w * 16) * 128;
      char* vdst = kdst + 8192;
      load_lds16(ksrc + (size_t)((kb + 1) * 64) * 1024, kdst);
      load_lds16(ksrc + (size_t)((kb + 1) * 64 + 8) * 1024, kdst + 1024);
      load_lds16(vsrc + (kb + 1) * 64, vdst);
      load_lds16(vsrc + 8 * SPAD + (kb + 1) * 64, vdst + 1024);
    }

    f32x4 s4[2][4];
    #pragma unroll
    for (int half = 0; half < 2; ++half)
      #pragma unroll
      for (int cf = 0; cf < 4; ++cf) s4[half][cf] = (f32x4)0.0f;
    #pragma unroll
    for (int kk = 0; kk < 2; ++kk)
      #pragma unroll
      for (int cf = 0; cf < 4; ++cf) {
        const bf16x8 af = *(const bf16x8*)(kbuf + (cf * 16 + fr) * 128 + ((kk * 64 + g * 16) ^ sw));
        s4[0][cf] = __builtin_amdgcn_mfma_f32_16x16x32_bf16(af, bq[0][kk], s4[0][cf], 0, 0, 0);
        s4[1][cf] = __builtin_amdgcn_mfma_f32_16x16x32_bf16(af, bq[1][kk], s4[1][cf], 0, 0, 0);
      }

    if (kb == 9) {
      #pragma unroll
      for (int half = 0; half < 2; ++half) {
        #pragma unroll
        for (int cf = 0; cf < 4; ++cf)
          #pragma unroll
          for (int r = 0; r < 4; ++r)
            if (cf != 0 || r != 0) s4[half][cf][r] = -__builtin_inff();
        s4[half][0][0] = (g == 0) ? s4[half][0][0] : -__builtin_inff();
      }
    }

    bf16x8 ap[2][2];
    #pragma unroll
    for (int half = 0; half < 2; ++half) {
      float sum = 0.0f;
      #pragma unroll
      for (int cf = 0; cf < 4; ++cf)
        #pragma unroll
        for (int r = 0; r < 4; ++r) {
          const float p2 = __builtin_amdgcn_exp2f(s4[half][cf][r]);
          s4[half][cf][r] = p2;
          sum += p2;
        }
      sum += __shfl_xor(sum, 16);
      sum += __shfl_xor(sum, 32);
      l_run[half] += sum;

      unsigned int pka[4], pkb[4];
      #pragma unroll
      for (int cf = 0; cf < 4; ++cf) {
        asm("v_cvt_pk_bf16_f32 %0, %1, %2" : "=v"(pka[cf]) : "v"(s4[half][cf][0]), "v"(s4[half][cf][1]));
        asm("v_cvt_pk_bf16_f32 %0, %1, %2" : "=v"(pkb[cf]) : "v"(s4[half][cf][2]), "v"(s4[half][cf][3]));
      }
      #pragma unroll
      for (int kk = 0; kk < 2; ++kk) {
        unsigned int a0 = pka[2 * kk], b0 = pka[2 * kk + 1];
        unsigned int a1 = pkb[2 * kk], b1 = pkb[2 * kk + 1];
        asm("v_permlane32_swap_b32 %0, %1" : "+v"(a0), "+v"(b0));
        asm("v_permlane16_swap_b32 %0, %1" : "+v"(a0), "+v"(b0));
        asm("v_permlane32_swap_b32 %0, %1" : "+v"(a1), "+v"(b1));
        asm("v_permlane16_swap_b32 %0, %1" : "+v"(a1), "+v"(b1));
        union { unsigned int i[4]; bf16x8 v; } u;
        u.i[0] = a0; u.i[1] = a1; u.i[2] = b0; u.i[3] = b1;
        ap[half][kk] = u.v;
      }
    }

    #pragma unroll
    for (int kk = 0; kk < 2; ++kk)
      #pragma unroll
      for (int cf = 0; cf < 4; ++cf) {
        const bf16x8 bv = *(const bf16x8*)(vbuf + (cf * 16 + fr) * 128 + ((kk * 64 + g * 16) ^ sw));
        acc[0][cf] = __builtin_amdgcn_mfma_f32_16x16x32_bf16(ap[0][kk], bv, acc[0][cf], 0, 0, 0);
        acc[1][cf] = __builtin_amdgcn_mfma_f32_16x16x32_bf16(ap[1][kk], bv, acc[1][cf], 0, 0, 0);
      }

    __syncthreads();
  }

  #pragma unroll
  for (int half = 0; half < 2; ++half) {
    const float rcp = 1.0f / l_run[half];
    #pragma unroll
    for (int r = 0; r < 4; ++r) {
      const float rr = __shfl(rcp, g * 4 + r);
      const int qg = qb * 128 + half * 64 + w * 16 + g * 4 + r;
      if (qg < SEQ) {
        #pragma unroll
        for (int cf = 0; cf < 4; ++cf)
          out[(rowbase + qg) * 1024 + h * 64 + cf * 16 + fr] = f2bf(acc[half][cf][r] * rr);
      }
    }
  }
}

extern "C" void kernel_launch(void* const* d_in, const int* in_sizes, int n_in,
                              void* d_out, int out_size, void* d_ws, size_t ws_size,
                              hipStream_t stream) {
  const float* x     = (const float*)d_in[0];
  const float* ln_g  = (const float*)d_in[1];
  const float* ln_b  = (const float*)d_in[2];
  const float* w_in  = (const float*)d_in[3];
  const float* b_in  = (const float*)d_in[4];
  const float* w_out = (const float*)d_in[5];
  const float* b_out = (const float*)d_in[6];

  unsigned short* z    = (unsigned short*)d_ws;            // [MROWS][1024] bf16; reused as attn_out
  unsigned short* qbuf = z + (size_t)MROWS * 1024;         // [MROWS][1024] bf16 (q = k, pre-scaled)
  unsigned short* vt   = qbuf + (size_t)MROWS * 1024;      // [32*1024][640] bf16 (V^T)
  unsigned short* wqv  = vt + (size_t)512 * 64 * SPAD;     // [2048][1024] bf16
  unsigned short* wo   = wqv + (size_t)2048 * 1024;        // [1024][1024] bf16

  ln_kernel<<<MROWS, 256, 0, stream>>>(x, ln_g, ln_b, z);
  conv_kernel<<<4096, 256, 0, stream>>>(w_in, w_out, wqv, wo, vt);
  gemm256<0><<<584, 1024, 0, stream>>>(z, wqv, b_in, qbuf, vt);
  attn_kernel<<<2560, 256, 0, stream>>>(qbuf, vt, z);
  gemm256<1><<<292, 1024, 0, stream>>>(z, wo, b_out, d_out, nullptr);
}